// Round 6
// baseline (560.275 us; speedup 1.0000x reference)
//
#include <hip/hip_runtime.h>
#include <stdint.h>

// Problem constants (fixed by the reference)
#define NN 2048      // nodes
#define DE 16        // embedding dim
#define BB 64        // batch
#define CC 64        // in channels
#define OO 64        // out channels
#define BC 4096      // BB*CC
#define KR 192       // K*CC = 3*64 reduction length
#define JJ 12288     // KR*OO

using bf16x8 = __attribute__((ext_vector_type(8))) __bf16;
using f32x4  = __attribute__((ext_vector_type(4))) float;

__device__ __forceinline__ unsigned short f2bf(float f) {
  union { float f; unsigned int u; } v; v.f = f;
  unsigned int u = v.u;
  return (unsigned short)((u + 0x7FFFu + ((u >> 16) & 1u)) >> 16);  // RNE
}
__device__ __forceinline__ float bf2f(unsigned short h) {
  union { unsigned int u; float f; } v; v.u = ((unsigned int)h) << 16;
  return v.f;
}
// async global->LDS, 16B per lane (used by one-shot make_w staging only).
__device__ __forceinline__ void gll16(const void* g, void* l) {
  __builtin_amdgcn_global_load_lds(
      (const __attribute__((address_space(1))) unsigned int*)g,
      (__attribute__((address_space(3))) unsigned int*)l, 16, 0, 0);
}

// ---------------------------------------------------------------------------
// Kernel 1 ("prep"):
//   blocks [0,2048):    pack feat [B,N,C] fp32 -> Fbf [N][B*C] bf16 + FbfT [B*C][N]
//   blocks [2048,2560): adjacency softmax(relu(E E^T)), 4 rows per block
//                       (E re-read 256->64 MB vs 1-row version); Bias = E@bp; Ebf
//   blocks [2560,2584): permute wp fp32 -> wpT2[j][16] bf16, j = rq*512+o*8+rl
__global__ __launch_bounds__(256) void prep(const float* __restrict__ feat,
                                            const float* __restrict__ E,
                                            const float* __restrict__ wp,
                                            const float* __restrict__ bp,
                                            unsigned short* __restrict__ Fbf,
                                            unsigned short* __restrict__ FbfT,
                                            unsigned short* __restrict__ Abf,
                                            float* __restrict__ Bias,
                                            unsigned short* __restrict__ Ebf,
                                            unsigned short* __restrict__ wpT2) {
  __shared__ float smem[64 * 65];  // 16.6 KB, reused per branch
  const int id = blockIdx.x;
  const int t  = threadIdx.x;

  if (id < 2048) {
    // ---- pack_feat: b = id>>5, n-tile = (id&31)*64 ----
    float (*tile)[65] = (float (*)[65])smem;  // +1 pad: conflict-free column reads
    const int b  = id >> 5;
    const int n0 = (id & 31) * 64;
    const int tr = t >> 4, tc4 = (t & 15) * 4;
#pragma unroll
    for (int i = 0; i < 4; ++i) {
      const int r = tr + i * 16;
      const float4 v = *(const float4*)(feat + (size_t)b * (NN * CC) + (size_t)(n0 + r) * CC + tc4);
      tile[r][tc4 + 0] = v.x; tile[r][tc4 + 1] = v.y;
      tile[r][tc4 + 2] = v.z; tile[r][tc4 + 3] = v.w;
    }
    __syncthreads();
#pragma unroll
    for (int i = 0; i < 4; ++i) {
      const int r = tr + i * 16;
      const unsigned int lo = f2bf(tile[r][tc4 + 0]) | ((unsigned int)f2bf(tile[r][tc4 + 1]) << 16);
      const unsigned int hi = f2bf(tile[r][tc4 + 2]) | ((unsigned int)f2bf(tile[r][tc4 + 3]) << 16);
      *(uint2*)(Fbf + (size_t)(n0 + r) * BC + b * CC + tc4) = make_uint2(lo, hi);
    }
    // transposed store, 8B per lane (4 consecutive n)
#pragma unroll
    for (int u = 0; u < 4; ++u) {
      const int p = t + u * 256;
      const int c = p >> 4, n4 = (p & 15) * 4;
      const unsigned int lo = f2bf(tile[n4 + 0][c]) | ((unsigned int)f2bf(tile[n4 + 1][c]) << 16);
      const unsigned int hi = f2bf(tile[n4 + 2][c]) | ((unsigned int)f2bf(tile[n4 + 3][c]) << 16);
      *(uint2*)(FbfT + (size_t)(b * CC + c) * NN + n0 + n4) = make_uint2(lo, hi);
    }
  } else if (id < 2560) {
    // ---- adj_softmax, 4 rows per block: n = n0base..n0base+3 ----
    const int n0base = (id - 2048) * 4;
    float* esm  = smem;        // [64] E rows n0base..+3
    float* redm = smem + 64;   // [16] max reduce
    float* reds = smem + 80;   // [16] sum reduce
    if (t < 64) esm[t] = E[n0base * 16 + t];
    __syncthreads();
    if (t < 64) Ebf[n0base * 16 + t] = f2bf(esm[t]);
    float er[4][16];
#pragma unroll
    for (int rr = 0; rr < 4; ++rr)
#pragma unroll
      for (int d = 0; d < 16; ++d) er[rr][d] = esm[rr * 16 + d];

    float v[8][4];
    float mx[4] = {0.f, 0.f, 0.f, 0.f};  // relu floor
#pragma unroll
    for (int i = 0; i < 8; ++i) {
      const int m = t + i * 256;
      const float4* Em = (const float4*)(E + m * 16);
      const float4 a = Em[0], b = Em[1], c = Em[2], d = Em[3];
#pragma unroll
      for (int rr = 0; rr < 4; ++rr) {
        float dot = er[rr][0] * a.x + er[rr][1] * a.y + er[rr][2] * a.z + er[rr][3] * a.w
                  + er[rr][4] * b.x + er[rr][5] * b.y + er[rr][6] * b.z + er[rr][7] * b.w
                  + er[rr][8] * c.x + er[rr][9] * c.y + er[rr][10] * c.z + er[rr][11] * c.w
                  + er[rr][12] * d.x + er[rr][13] * d.y + er[rr][14] * d.z + er[rr][15] * d.w;
        const float r = fmaxf(dot, 0.0f);
        v[i][rr] = r;
        mx[rr] = fmaxf(mx[rr], r);
      }
    }
    const int wave = t >> 6, lane = t & 63;
#pragma unroll
    for (int rr = 0; rr < 4; ++rr) {
#pragma unroll
      for (int off = 32; off > 0; off >>= 1) mx[rr] = fmaxf(mx[rr], __shfl_xor(mx[rr], off, 64));
      if (lane == 0) redm[wave * 4 + rr] = mx[rr];
    }
    __syncthreads();
#pragma unroll
    for (int rr = 0; rr < 4; ++rr)
      mx[rr] = fmaxf(fmaxf(redm[rr], redm[4 + rr]), fmaxf(redm[8 + rr], redm[12 + rr]));
    float s[4] = {0.f, 0.f, 0.f, 0.f};
#pragma unroll
    for (int i = 0; i < 8; ++i)
#pragma unroll
      for (int rr = 0; rr < 4; ++rr) { v[i][rr] = __expf(v[i][rr] - mx[rr]); s[rr] += v[i][rr]; }
#pragma unroll
    for (int rr = 0; rr < 4; ++rr) {
#pragma unroll
      for (int off = 32; off > 0; off >>= 1) s[rr] += __shfl_xor(s[rr], off, 64);
      if (lane == 0) reds[wave * 4 + rr] = s[rr];
    }
    __syncthreads();
    float inv[4];
#pragma unroll
    for (int rr = 0; rr < 4; ++rr)
      inv[rr] = 1.0f / (reds[rr] + reds[4 + rr] + reds[8 + rr] + reds[12 + rr]);
#pragma unroll
    for (int i = 0; i < 8; ++i)
#pragma unroll
      for (int rr = 0; rr < 4; ++rr)
        Abf[(size_t)(n0base + rr) * NN + t + i * 256] = f2bf(v[i][rr] * inv[rr]);
    if (t < 64) {
#pragma unroll
      for (int rr = 0; rr < 4; ++rr) {
        float bs = 0.0f;
#pragma unroll
        for (int d = 0; d < 16; ++d) bs += esm[rr * 16 + d] * bp[d * 64 + t];
        Bias[(size_t)(n0base + rr) * 64 + t] = bs;
      }
    }
  } else {
    // ---- wp permute: block rq handles j in [rq*512, rq*512+512), all 16 d ----
    const int rq = id - 2560;
    for (int p = t; p < 1024; p += 256) {
      const int e0 = p * 8;
      const int d0 = e0 & 15;        // 0 or 8
      const int rem = e0 >> 4;       // o*8 + rl
      const int rl = rem & 7, o = rem >> 3;
      const int r = rq * 8 + rl;
      unsigned int w[4];
#pragma unroll
      for (int u = 0; u < 4; ++u) {
        const float f0 = wp[(size_t)(d0 + 2 * u) * JJ + r * 64 + o];
        const float f1 = wp[(size_t)(d0 + 2 * u + 1) * JJ + r * 64 + o];
        w[u] = f2bf(f0) | ((unsigned int)f2bf(f1) << 16);
      }
      *(uint4*)(wpT2 + (size_t)rq * 8192 + e0) = make_uint4(w[0], w[1], w[2], w[3]);
    }
  }
}

// ---------------------------------------------------------------------------
// Kernel 2: 128Mx64N BK=64 bf16 MFMA GEMM, register-staged double buffer:
// slab k+1 is loaded into VGPRs (plain global_load_dwordx4, stays in flight
// through the MFMA phase); between barriers only ds_write sits (short lgkm
// drain) — removes the global_load_lds vmcnt(0) barrier drain that pinned
// rounds 1-5 at 55-59us. R4 block mapping (locality-agnostic; the R5 XCD
// swizzle tripled L2-miss traffic — workgroup->XCD mapping is undefined).
// LDS XOR swizzle phys = logical ^ ((row>>1)&7): 0 conflicts (measured R3).
// EPI=1: store G1 node-major + G1T. EPI=2: store G2 = 2*acc - F; blocks
// [1024,2560) of the EPI=2 dispatch run make_w (Wg = Ebf @ wpT2^T).
template <int EPI, int MW>
__global__ __launch_bounds__(256, 4) void gemm_mw(const unsigned short* __restrict__ A,
                                                  const unsigned short* __restrict__ Bt,
                                                  unsigned short* __restrict__ Cnm,
                                                  unsigned short* __restrict__ Ct,
                                                  const unsigned short* __restrict__ F,
                                                  const unsigned short* __restrict__ Ebf,
                                                  const unsigned short* __restrict__ wpT2,
                                                  unsigned short* __restrict__ Wg) {
  __shared__ alignas(16) unsigned short As[128 * 64];  // 16KB
  __shared__ alignas(16) unsigned short Bs[64 * 64];   // 8KB
  const int id = blockIdx.x;
  const int t = threadIdx.x;
  const int wave = t >> 6, lane = t & 63;
  const int li = lane & 15, q = lane >> 4;

  if (MW && id >= 1024) {
    // ---- make_w: Wg[n][j] = sum_d Ebf[n][d] * wpT2[j][d], K=32 (hi 16 zero) ----
    const int wid = id - 1024;
    const int bj = (wid % 96) * 128;
    const int bm = (wid / 96) * 128;
    gll16(Ebf  + (size_t)(bm + (t >> 1)) * 16 + (t & 1) * 8, &As[t * 8]);
    gll16(wpT2 + (size_t)(bj + (t >> 1)) * 16 + (t & 1) * 8, &Bs[t * 8]);
    __syncthreads();
    const int wm = (wave >> 1) * 64, wj = (wave & 1) * 64;
    const bool hiK = (q >= 2);
    const int qq = q & 1;
    bf16x8 vz;
#pragma unroll
    for (int i = 0; i < 8; ++i) vz[i] = (__bf16)0.0f;
    bf16x8 af[4], bfr[4];
#pragma unroll
    for (int r = 0; r < 4; ++r) {
      af[r] = *(const bf16x8*)&As[(wm + r * 16 + li) * 16 + qq * 8];
      if (hiK) af[r] = vz;
    }
#pragma unroll
    for (int c = 0; c < 4; ++c) {
      bfr[c] = *(const bf16x8*)&Bs[(wj + c * 16 + li) * 16 + qq * 8];
      if (hiK) bfr[c] = vz;
    }
    const int rowL = q * 4;
#pragma unroll
    for (int r = 0; r < 4; ++r) {
#pragma unroll
      for (int c = 0; c < 4; ++c) {
        f32x4 acc = (f32x4){0.f, 0.f, 0.f, 0.f};
        acc = __builtin_amdgcn_mfma_f32_16x16x32_bf16(af[r], bfr[c], acc, 0, 0, 0);
        const int gm = bm + wm + r * 16 + rowL;
        const int gj = bj + wj + c * 16 + li;
#pragma unroll
        for (int i = 0; i < 4; ++i)
          Wg[(size_t)(gm + i) * JJ + gj] = f2bf(acc[i]);
      }
    }
    return;
  }

  // ---- GEMM: R4 mapping bm=(id>>6)*128, bn=(id&63)*64 ----
  const int bm = (id >> 6) * 128, bn = (id & 63) * 64;
  const int wm = wave * 32;  // wave covers 32 M-rows x 64 N-cols

  f32x4 acc[2][4];
#pragma unroll
  for (int r = 0; r < 2; ++r)
#pragma unroll
    for (int c = 0; c < 4; ++c) acc[r][c] = (f32x4){0.f, 0.f, 0.f, 0.f};

  // staging: thread t owns LDS chunks t+256i (A: i=0..3, B: i=0..1), 16B each.
  // chunk c: row = c>>3, pos = c&7; phys pos holds logical pos ^ ((row>>1)&7).
  const int srow = t >> 3;
  const int csw = (((t & 7) ^ ((t >> 4) & 7)) * 8);        // swizzled col (elems)
  const unsigned short* Ap[4];
  const unsigned short* Bp[2];
#pragma unroll
  for (int i = 0; i < 4; ++i) Ap[i] = A + (size_t)(bm + srow + i * 32) * NN + csw;
#pragma unroll
  for (int i = 0; i < 2; ++i) Bp[i] = Bt + (size_t)(bn + srow + i * 32) * NN + csw;
  const int sw = (li >> 1) & 7;

  uint4 ra[4], rb[2];
#pragma unroll
  for (int i = 0; i < 4; ++i) ra[i] = *(const uint4*)(Ap[i]);
#pragma unroll
  for (int i = 0; i < 2; ++i) rb[i] = *(const uint4*)(Bp[i]);

  for (int k0 = 0; k0 < NN; k0 += 64) {
    __syncthreads();  // prior-iter LDS reads done before overwrite
#pragma unroll
    for (int i = 0; i < 4; ++i) *(uint4*)&As[(t + i * 256) * 8] = ra[i];
#pragma unroll
    for (int i = 0; i < 2; ++i) *(uint4*)&Bs[(t + i * 256) * 8] = rb[i];
    // issue next-slab loads now; they stay in flight through the MFMA phase
    const int kn = (k0 + 64 < NN) ? (k0 + 64) : 0;  // wrap: harmless dummy reload
#pragma unroll
    for (int i = 0; i < 4; ++i) ra[i] = *(const uint4*)(Ap[i] + kn);
#pragma unroll
    for (int i = 0; i < 2; ++i) rb[i] = *(const uint4*)(Bp[i] + kn);
    __syncthreads();  // ds_writes visible (lgkm drain only)
#pragma unroll
    for (int kk = 0; kk < 2; ++kk) {
      const int kc = ((kk * 4 + q) ^ sw) * 8;
      bf16x8 af[2], bfr[4];
#pragma unroll
      for (int r = 0; r < 2; ++r)
        af[r] = *(const bf16x8*)&As[(wm + r * 16 + li) * 64 + kc];
#pragma unroll
      for (int c = 0; c < 4; ++c)
        bfr[c] = *(const bf16x8*)&Bs[(c * 16 + li) * 64 + kc];
#pragma unroll
      for (int r = 0; r < 2; ++r)
#pragma unroll
        for (int c = 0; c < 4; ++c)
          acc[r][c] = __builtin_amdgcn_mfma_f32_16x16x32_bf16(af[r], bfr[c], acc[r][c], 0, 0, 0);
    }
  }

  const int rowL = q * 4;  // C/D: col=lane&15, row=quad*4+i
#pragma unroll
  for (int r = 0; r < 2; ++r) {
#pragma unroll
    for (int c = 0; c < 4; ++c) {
      const int gm = bm + wm + r * 16 + rowL;
      const int gn = bn + c * 16 + li;
      const f32x4 a = acc[r][c];
      if (EPI == 1) {
#pragma unroll
        for (int i = 0; i < 4; ++i)
          Cnm[(size_t)(gm + i) * BC + gn] = f2bf(a[i]);
        const unsigned int lo = f2bf(a[0]) | ((unsigned int)f2bf(a[1]) << 16);
        const unsigned int hi = f2bf(a[2]) | ((unsigned int)f2bf(a[3]) << 16);
        *(uint2*)(Ct + (size_t)gn * NN + gm) = make_uint2(lo, hi);  // gm%4==0 -> 8B aligned
      } else {
#pragma unroll
        for (int i = 0; i < 4; ++i) {
          const float g = 2.0f * a[i] - bf2f(F[(size_t)(gm + i) * BC + gn]);
          Cnm[(size_t)(gm + i) * BC + gn] = f2bf(g);
        }
      }
    }
  }
}

// ---------------------------------------------------------------------------
// Kernel 3: per-node GEMM out[b,n,o] = X_n[64,192] @ W_n[192,64] + bias[n,o].
// LDS-free, barrier-free: K8-blocked Wg + node-major X make every MFMA
// fragment a coalesced 16B global load (direct global->VGPR).
__global__ __launch_bounds__(256, 6) void final_gemm(const unsigned short* __restrict__ Fbf,
                                                     const unsigned short* __restrict__ G1,
                                                     const unsigned short* __restrict__ G2,
                                                     const unsigned short* __restrict__ Wg,
                                                     const float* __restrict__ Bias,
                                                     float* __restrict__ out) {
  const int n = blockIdx.x, t = threadIdx.x;
  const int wave = t >> 6, lane = t & 63;
  const int li = lane & 15, q = lane >> 4;
  const unsigned short* xb[3] = {Fbf + (size_t)n * BC + (size_t)(wave * 16 + li) * 64,
                                 G1  + (size_t)n * BC + (size_t)(wave * 16 + li) * 64,
                                 G2  + (size_t)n * BC + (size_t)(wave * 16 + li) * 64};
  const unsigned short* wb = Wg + (size_t)n * JJ + (size_t)q * 512 + li * 8;

  f32x4 acc[4];
#pragma unroll
  for (int c = 0; c < 4; ++c) acc[c] = (f32x4){0.f, 0.f, 0.f, 0.f};
#pragma unroll
  for (int kq = 0; kq < 6; ++kq) {
    const bf16x8 a = *(const bf16x8*)(xb[kq >> 1] + (kq & 1) * 32 + q * 8);
#pragma unroll
    for (int c = 0; c < 4; ++c) {
      const bf16x8 b = *(const bf16x8*)(wb + (size_t)kq * 2048 + c * 128);
      acc[c] = __builtin_amdgcn_mfma_f32_16x16x32_bf16(a, b, acc[c], 0, 0, 0);
    }
  }
  const int rbase = wave * 16 + q * 4;
#pragma unroll
  for (int c = 0; c < 4; ++c) {
    const int o = c * 16 + li;
    const float bs = Bias[n * 64 + o];
#pragma unroll
    for (int i = 0; i < 4; ++i)
      out[(size_t)(rbase + i) * (NN * OO) + (size_t)n * OO + o] = acc[c][i] + bs;
  }
}

// ---------------------------------------------------------------------------
extern "C" void kernel_launch(void* const* d_in, const int* in_sizes, int n_in,
                              void* d_out, int out_size, void* d_ws, size_t ws_size,
                              hipStream_t stream) {
  const float* E    = (const float*)d_in[0];  // [2048,16]
  const float* feat = (const float*)d_in[1];  // [64,2048,64]
  const float* wp   = (const float*)d_in[2];  // [16,3,64,64]
  const float* bp   = (const float*)d_in[3];  // [16,64]
  float* out = (float*)d_out;

  char* ws = (char*)d_ws;
  size_t off = 0;
  auto alloc = [&](size_t bytes) -> void* {
    void* p = ws + off;
    off += (bytes + 255) & ~(size_t)255;
    return p;
  };
  unsigned short* Abf  = (unsigned short*)alloc((size_t)NN * NN * 2);   //  8 MB
  unsigned short* FbfT = (unsigned short*)alloc((size_t)BC * NN * 2);   // 16 MB (reused as G2)
  unsigned short* Fbf  = (unsigned short*)alloc((size_t)NN * BC * 2);   // 16 MB
  unsigned short* G1   = (unsigned short*)alloc((size_t)NN * BC * 2);   // 16 MB
  unsigned short* G1T  = (unsigned short*)alloc((size_t)BC * NN * 2);   // 16 MB
  unsigned short* Wg   = (unsigned short*)alloc((size_t)NN * JJ * 2);   // 48 MB
  float* Bias          = (float*)alloc((size_t)NN * OO * 4);            // 0.5 MB
  unsigned short* Ebf  = (unsigned short*)alloc((size_t)NN * DE * 2);   // 64 KB
  unsigned short* wpT2 = (unsigned short*)alloc((size_t)JJ * DE * 2);   // 384 KB
  unsigned short* G2   = FbfT;  // FbfT dead after GEMM1; GEMM2 reads G1T/Abf/Fbf only

  prep<<<dim3(2584), 256, 0, stream>>>(feat, E, wp, bp, Fbf, FbfT, Abf, Bias, Ebf, wpT2);
  gemm_mw<1, 0><<<dim3(1024), 256, 0, stream>>>(Abf, FbfT, G1, G1T, nullptr, Ebf, wpT2, Wg);
  gemm_mw<2, 1><<<dim3(2560), 256, 0, stream>>>(Abf, G1T, G2, nullptr, Fbf, Ebf, wpT2, Wg);
  final_gemm<<<dim3(2048), 256, 0, stream>>>(Fbf, G1, G2, Wg, Bias, out);
}

// Round 7
// 262.796 us; speedup vs baseline: 2.1320x; 2.1320x over previous
//
#include <hip/hip_runtime.h>
#include <stdint.h>

// Problem constants (fixed by the reference)
#define NN 2048      // nodes
#define DE 16        // embedding dim
#define BB 64        // batch
#define CC 64        // in channels
#define OO 64        // out channels
#define BC 4096      // BB*CC
#define KR 192       // K*CC = 3*64 reduction length
#define JJ 12288     // KR*OO

using bf16x8 = __attribute__((ext_vector_type(8))) __bf16;
using f32x4  = __attribute__((ext_vector_type(4))) float;

__device__ __forceinline__ unsigned short f2bf(float f) {
  union { float f; unsigned int u; } v; v.f = f;
  unsigned int u = v.u;
  return (unsigned short)((u + 0x7FFFu + ((u >> 16) & 1u)) >> 16);  // RNE
}
__device__ __forceinline__ float bf2f(unsigned short h) {
  union { unsigned int u; float f; } v; v.u = ((unsigned int)h) << 16;
  return v.f;
}
// async global->LDS, 16B per lane. LDS dst is wave-uniform base + lane*16.
__device__ __forceinline__ void gll16(const void* g, void* l) {
  __builtin_amdgcn_global_load_lds(
      (const __attribute__((address_space(1))) unsigned int*)g,
      (__attribute__((address_space(3))) unsigned int*)l, 16, 0, 0);
}

// ---------------------------------------------------------------------------
// Kernel 1 ("prep"):
//   blocks [0,2048):    pack feat [B,N,C] fp32 -> Fbf [N][B*C] bf16 + FbfT [B*C][N]
//   blocks [2048,2560): adjacency softmax(relu(E E^T)), 4 rows per block; Bias; Ebf
//   blocks [2560,2584): permute wp fp32 -> wpT2[j][16] bf16, j = rq*512+o*8+rl
__global__ __launch_bounds__(256) void prep(const float* __restrict__ feat,
                                            const float* __restrict__ E,
                                            const float* __restrict__ wp,
                                            const float* __restrict__ bp,
                                            unsigned short* __restrict__ Fbf,
                                            unsigned short* __restrict__ FbfT,
                                            unsigned short* __restrict__ Abf,
                                            float* __restrict__ Bias,
                                            unsigned short* __restrict__ Ebf,
                                            unsigned short* __restrict__ wpT2) {
  __shared__ float smem[64 * 65];  // 16.6 KB, reused per branch
  const int id = blockIdx.x;
  const int t  = threadIdx.x;

  if (id < 2048) {
    // ---- pack_feat: b = id>>5, n-tile = (id&31)*64 ----
    float (*tile)[65] = (float (*)[65])smem;  // +1 pad: conflict-free column reads
    const int b  = id >> 5;
    const int n0 = (id & 31) * 64;
    const int tr = t >> 4, tc4 = (t & 15) * 4;
#pragma unroll
    for (int i = 0; i < 4; ++i) {
      const int r = tr + i * 16;
      const float4 v = *(const float4*)(feat + (size_t)b * (NN * CC) + (size_t)(n0 + r) * CC + tc4);
      tile[r][tc4 + 0] = v.x; tile[r][tc4 + 1] = v.y;
      tile[r][tc4 + 2] = v.z; tile[r][tc4 + 3] = v.w;
    }
    __syncthreads();
#pragma unroll
    for (int i = 0; i < 4; ++i) {
      const int r = tr + i * 16;
      const unsigned int lo = f2bf(tile[r][tc4 + 0]) | ((unsigned int)f2bf(tile[r][tc4 + 1]) << 16);
      const unsigned int hi = f2bf(tile[r][tc4 + 2]) | ((unsigned int)f2bf(tile[r][tc4 + 3]) << 16);
      *(uint2*)(Fbf + (size_t)(n0 + r) * BC + b * CC + tc4) = make_uint2(lo, hi);
    }
    // transposed store, 8B per lane (4 consecutive n)
#pragma unroll
    for (int u = 0; u < 4; ++u) {
      const int p = t + u * 256;
      const int c = p >> 4, n4 = (p & 15) * 4;
      const unsigned int lo = f2bf(tile[n4 + 0][c]) | ((unsigned int)f2bf(tile[n4 + 1][c]) << 16);
      const unsigned int hi = f2bf(tile[n4 + 2][c]) | ((unsigned int)f2bf(tile[n4 + 3][c]) << 16);
      *(uint2*)(FbfT + (size_t)(b * CC + c) * NN + n0 + n4) = make_uint2(lo, hi);
    }
  } else if (id < 2560) {
    // ---- adj_softmax, 4 rows per block (correctness verified in round 6) ----
    const int n0base = (id - 2048) * 4;
    float* esm  = smem;        // [64]
    float* redm = smem + 64;   // [16]
    float* reds = smem + 80;   // [16]
    if (t < 64) esm[t] = E[n0base * 16 + t];
    __syncthreads();
    if (t < 64) Ebf[n0base * 16 + t] = f2bf(esm[t]);
    float er[4][16];
#pragma unroll
    for (int rr = 0; rr < 4; ++rr)
#pragma unroll
      for (int d = 0; d < 16; ++d) er[rr][d] = esm[rr * 16 + d];

    float v[8][4];
    float mx[4] = {0.f, 0.f, 0.f, 0.f};  // relu floor
#pragma unroll
    for (int i = 0; i < 8; ++i) {
      const int m = t + i * 256;
      const float4* Em = (const float4*)(E + m * 16);
      const float4 a = Em[0], b = Em[1], c = Em[2], d = Em[3];
#pragma unroll
      for (int rr = 0; rr < 4; ++rr) {
        float dot = er[rr][0] * a.x + er[rr][1] * a.y + er[rr][2] * a.z + er[rr][3] * a.w
                  + er[rr][4] * b.x + er[rr][5] * b.y + er[rr][6] * b.z + er[rr][7] * b.w
                  + er[rr][8] * c.x + er[rr][9] * c.y + er[rr][10] * c.z + er[rr][11] * c.w
                  + er[rr][12] * d.x + er[rr][13] * d.y + er[rr][14] * d.z + er[rr][15] * d.w;
        const float r = fmaxf(dot, 0.0f);
        v[i][rr] = r;
        mx[rr] = fmaxf(mx[rr], r);
      }
    }
    const int wave = t >> 6, lane = t & 63;
#pragma unroll
    for (int rr = 0; rr < 4; ++rr) {
#pragma unroll
      for (int off = 32; off > 0; off >>= 1) mx[rr] = fmaxf(mx[rr], __shfl_xor(mx[rr], off, 64));
      if (lane == 0) redm[wave * 4 + rr] = mx[rr];
    }
    __syncthreads();
#pragma unroll
    for (int rr = 0; rr < 4; ++rr)
      mx[rr] = fmaxf(fmaxf(redm[rr], redm[4 + rr]), fmaxf(redm[8 + rr], redm[12 + rr]));
    float s[4] = {0.f, 0.f, 0.f, 0.f};
#pragma unroll
    for (int i = 0; i < 8; ++i)
#pragma unroll
      for (int rr = 0; rr < 4; ++rr) { v[i][rr] = __expf(v[i][rr] - mx[rr]); s[rr] += v[i][rr]; }
#pragma unroll
    for (int rr = 0; rr < 4; ++rr) {
#pragma unroll
      for (int off = 32; off > 0; off >>= 1) s[rr] += __shfl_xor(s[rr], off, 64);
      if (lane == 0) reds[wave * 4 + rr] = s[rr];
    }
    __syncthreads();
    float inv[4];
#pragma unroll
    for (int rr = 0; rr < 4; ++rr)
      inv[rr] = 1.0f / (reds[rr] + reds[4 + rr] + reds[8 + rr] + reds[12 + rr]);
#pragma unroll
    for (int i = 0; i < 8; ++i)
#pragma unroll
      for (int rr = 0; rr < 4; ++rr)
        Abf[(size_t)(n0base + rr) * NN + t + i * 256] = f2bf(v[i][rr] * inv[rr]);
    if (t < 64) {
#pragma unroll
      for (int rr = 0; rr < 4; ++rr) {
        float bs = 0.0f;
#pragma unroll
        for (int d = 0; d < 16; ++d) bs += esm[rr * 16 + d] * bp[d * 64 + t];
        Bias[(size_t)(n0base + rr) * 64 + t] = bs;
      }
    }
  } else {
    // ---- wp permute: block rq handles j in [rq*512, rq*512+512), all 16 d ----
    const int rq = id - 2560;
    for (int p = t; p < 1024; p += 256) {
      const int e0 = p * 8;
      const int d0 = e0 & 15;        // 0 or 8
      const int rem = e0 >> 4;       // o*8 + rl
      const int rl = rem & 7, o = rem >> 3;
      const int r = rq * 8 + rl;
      unsigned int w[4];
#pragma unroll
      for (int u = 0; u < 4; ++u) {
        const float f0 = wp[(size_t)(d0 + 2 * u) * JJ + r * 64 + o];
        const float f1 = wp[(size_t)(d0 + 2 * u + 1) * JJ + r * 64 + o];
        w[u] = f2bf(f0) | ((unsigned int)f2bf(f1) << 16);
      }
      *(uint4*)(wpT2 + (size_t)rq * 8192 + e0) = make_uint4(w[0], w[1], w[2], w[3]);
    }
  }
}

// ---------------------------------------------------------------------------
// Kernel 2: 128Mx64N BK=64 bf16 MFMA GEMM — exact round-4 structure (gll16
// staging; measured 55-57us, 0 LDS conflicts). Register-staged dbuf (R6) and
// XCD swizzle (R5) both measured-rejected: spill disaster / 3x L2-miss.
// Blocks [1024, 1024+768) run make_w backfill (Wg = Ebf @ wpT2^T, K8-block
// j-layout), node range selected by mwbase — split across both dispatches.
// EPI=1: store G1 node-major + G1T. EPI=2: store G2 = 2*acc - F node-major.
template <int EPI>
__global__ __launch_bounds__(256, 6) void gemm_mw(const unsigned short* __restrict__ A,
                                                  const unsigned short* __restrict__ Bt,
                                                  unsigned short* __restrict__ Cnm,
                                                  unsigned short* __restrict__ Ct,
                                                  const unsigned short* __restrict__ F,
                                                  const unsigned short* __restrict__ Ebf,
                                                  const unsigned short* __restrict__ wpT2,
                                                  unsigned short* __restrict__ Wg,
                                                  int mwbase) {
  __shared__ alignas(16) unsigned short As[128 * 64];  // 16KB
  __shared__ alignas(16) unsigned short Bs[64 * 64];   // 8KB
  const int id = blockIdx.x;
  const int t = threadIdx.x;
  const int wave = t >> 6, lane = t & 63;
  const int li = lane & 15, q = lane >> 4;

  if (id >= 1024) {
    // ---- make_w: Wg[n][j] = sum_d Ebf[n][d] * wpT2[j][d], K=32 (hi 16 zero) ----
    const int wid = id - 1024 + mwbase;   // [0,1536) over both dispatches
    const int bj = (wid % 96) * 128;
    const int bm = (wid / 96) * 128;
    gll16(Ebf  + (size_t)(bm + (t >> 1)) * 16 + (t & 1) * 8, &As[t * 8]);
    gll16(wpT2 + (size_t)(bj + (t >> 1)) * 16 + (t & 1) * 8, &Bs[t * 8]);
    __syncthreads();
    const int wm = (wave >> 1) * 64, wj = (wave & 1) * 64;
    const bool hiK = (q >= 2);
    const int qq = q & 1;
    bf16x8 vz;
#pragma unroll
    for (int i = 0; i < 8; ++i) vz[i] = (__bf16)0.0f;
    bf16x8 af[4], bfr[4];
#pragma unroll
    for (int r = 0; r < 4; ++r) {
      af[r] = *(const bf16x8*)&As[(wm + r * 16 + li) * 16 + qq * 8];
      if (hiK) af[r] = vz;
    }
#pragma unroll
    for (int c = 0; c < 4; ++c) {
      bfr[c] = *(const bf16x8*)&Bs[(wj + c * 16 + li) * 16 + qq * 8];
      if (hiK) bfr[c] = vz;
    }
    const int rowL = q * 4;
#pragma unroll
    for (int r = 0; r < 4; ++r) {
#pragma unroll
      for (int c = 0; c < 4; ++c) {
        f32x4 acc = (f32x4){0.f, 0.f, 0.f, 0.f};
        acc = __builtin_amdgcn_mfma_f32_16x16x32_bf16(af[r], bfr[c], acc, 0, 0, 0);
        const int gm = bm + wm + r * 16 + rowL;
        const int gj = bj + wj + c * 16 + li;
#pragma unroll
        for (int i = 0; i < 4; ++i)
          Wg[(size_t)(gm + i) * JJ + gj] = f2bf(acc[i]);
      }
    }
    return;
  }

  // ---- GEMM: bm=(id>>6)*128, bn=(id&63)*64 (locality-agnostic mapping) ----
  const int bm = (id >> 6) * 128, bn = (id & 63) * 64;
  const int wm = wave * 32;  // wave covers 32 M-rows x 64 N-cols

  f32x4 acc[2][4];
#pragma unroll
  for (int r = 0; r < 2; ++r)
#pragma unroll
    for (int c = 0; c < 4; ++c) acc[r][c] = (f32x4){0.f, 0.f, 0.f, 0.f};

  // staging: A 1024 chunks (4/thread), B 512 chunks (2/thread), 16B each.
  // chunk c: row = c>>3, pos = c&7; phys pos holds logical pos ^ ((row>>1)&7).
  const int srow = t >> 3;
  const int csw = (((t & 7) ^ ((t >> 4) & 7)) * 8);        // swizzled col (elems)
  const unsigned short* Ap[4];
  const unsigned short* Bp[2];
#pragma unroll
  for (int i = 0; i < 4; ++i) Ap[i] = A + (size_t)(bm + srow + i * 32) * NN + csw;
#pragma unroll
  for (int i = 0; i < 2; ++i) Bp[i] = Bt + (size_t)(bn + srow + i * 32) * NN + csw;
  const int sw = (li >> 1) & 7;

  for (int k0 = 0; k0 < NN; k0 += 64) {
    __syncthreads();  // prior-iter LDS reads done before overwrite
#pragma unroll
    for (int i = 0; i < 4; ++i) gll16(Ap[i] + k0, &As[(t + i * 256) * 8]);
#pragma unroll
    for (int i = 0; i < 2; ++i) gll16(Bp[i] + k0, &Bs[(t + i * 256) * 8]);
    __syncthreads();  // compiler drains vmcnt before s_barrier
#pragma unroll
    for (int kk = 0; kk < 2; ++kk) {
      const int kc = ((kk * 4 + q) ^ sw) * 8;
      bf16x8 af[2], bfr[4];
#pragma unroll
      for (int r = 0; r < 2; ++r)
        af[r] = *(const bf16x8*)&As[(wm + r * 16 + li) * 64 + kc];
#pragma unroll
      for (int c = 0; c < 4; ++c)
        bfr[c] = *(const bf16x8*)&Bs[(c * 16 + li) * 64 + kc];
#pragma unroll
      for (int r = 0; r < 2; ++r)
#pragma unroll
        for (int c = 0; c < 4; ++c)
          acc[r][c] = __builtin_amdgcn_mfma_f32_16x16x32_bf16(af[r], bfr[c], acc[r][c], 0, 0, 0);
    }
  }

  const int rowL = q * 4;  // C/D: col=lane&15, row=quad*4+i
#pragma unroll
  for (int r = 0; r < 2; ++r) {
#pragma unroll
    for (int c = 0; c < 4; ++c) {
      const int gm = bm + wm + r * 16 + rowL;
      const int gn = bn + c * 16 + li;
      const f32x4 a = acc[r][c];
      if (EPI == 1) {
#pragma unroll
        for (int i = 0; i < 4; ++i)
          Cnm[(size_t)(gm + i) * BC + gn] = f2bf(a[i]);
        const unsigned int lo = f2bf(a[0]) | ((unsigned int)f2bf(a[1]) << 16);
        const unsigned int hi = f2bf(a[2]) | ((unsigned int)f2bf(a[3]) << 16);
        *(uint2*)(Ct + (size_t)gn * NN + gm) = make_uint2(lo, hi);  // gm%4==0 -> 8B aligned
      } else {
#pragma unroll
        for (int i = 0; i < 4; ++i) {
          const float g = 2.0f * a[i] - bf2f(F[(size_t)(gm + i) * BC + gn]);
          Cnm[(size_t)(gm + i) * BC + gn] = f2bf(g);
        }
      }
    }
  }
}

// ---------------------------------------------------------------------------
// Kernel 3: per-node GEMM out[b,n,o] = X_n[64,192] @ W_n[192,64] + bias[n,o].
// LDS-free, barrier-free (ran correct in rounds 5/6): K8-blocked Wg +
// node-major X make every MFMA fragment a coalesced 16B global load.
__global__ __launch_bounds__(256, 6) void final_gemm(const unsigned short* __restrict__ Fbf,
                                                     const unsigned short* __restrict__ G1,
                                                     const unsigned short* __restrict__ G2,
                                                     const unsigned short* __restrict__ Wg,
                                                     const float* __restrict__ Bias,
                                                     float* __restrict__ out) {
  const int n = blockIdx.x, t = threadIdx.x;
  const int wave = t >> 6, lane = t & 63;
  const int li = lane & 15, q = lane >> 4;
  const unsigned short* xb[3] = {Fbf + (size_t)n * BC + (size_t)(wave * 16 + li) * 64,
                                 G1  + (size_t)n * BC + (size_t)(wave * 16 + li) * 64,
                                 G2  + (size_t)n * BC + (size_t)(wave * 16 + li) * 64};
  const unsigned short* wb = Wg + (size_t)n * JJ + (size_t)q * 512 + li * 8;

  f32x4 acc[4];
#pragma unroll
  for (int c = 0; c < 4; ++c) acc[c] = (f32x4){0.f, 0.f, 0.f, 0.f};
#pragma unroll
  for (int kq = 0; kq < 6; ++kq) {
    const bf16x8 a = *(const bf16x8*)(xb[kq >> 1] + (kq & 1) * 32 + q * 8);
#pragma unroll
    for (int c = 0; c < 4; ++c) {
      const bf16x8 b = *(const bf16x8*)(wb + (size_t)kq * 2048 + c * 128);
      acc[c] = __builtin_amdgcn_mfma_f32_16x16x32_bf16(a, b, acc[c], 0, 0, 0);
    }
  }
  const int rbase = wave * 16 + q * 4;
#pragma unroll
  for (int c = 0; c < 4; ++c) {
    const int o = c * 16 + li;
    const float bs = Bias[n * 64 + o];
#pragma unroll
    for (int i = 0; i < 4; ++i)
      out[(size_t)(rbase + i) * (NN * OO) + (size_t)n * OO + o] = acc[c][i] + bs;
  }
}

// ---------------------------------------------------------------------------
extern "C" void kernel_launch(void* const* d_in, const int* in_sizes, int n_in,
                              void* d_out, int out_size, void* d_ws, size_t ws_size,
                              hipStream_t stream) {
  const float* E    = (const float*)d_in[0];  // [2048,16]
  const float* feat = (const float*)d_in[1];  // [64,2048,64]
  const float* wp   = (const float*)d_in[2];  // [16,3,64,64]
  const float* bp   = (const float*)d_in[3];  // [16,64]
  float* out = (float*)d_out;

  char* ws = (char*)d_ws;
  size_t off = 0;
  auto alloc = [&](size_t bytes) -> void* {
    void* p = ws + off;
    off += (bytes + 255) & ~(size_t)255;
    return p;
  };
  unsigned short* Abf  = (unsigned short*)alloc((size_t)NN * NN * 2);   //  8 MB
  unsigned short* FbfT = (unsigned short*)alloc((size_t)BC * NN * 2);   // 16 MB (reused as G2)
  unsigned short* Fbf  = (unsigned short*)alloc((size_t)NN * BC * 2);   // 16 MB
  unsigned short* G1   = (unsigned short*)alloc((size_t)NN * BC * 2);   // 16 MB
  unsigned short* G1T  = (unsigned short*)alloc((size_t)BC * NN * 2);   // 16 MB
  unsigned short* Wg   = (unsigned short*)alloc((size_t)NN * JJ * 2);   // 48 MB
  float* Bias          = (float*)alloc((size_t)NN * OO * 4);            // 0.5 MB
  unsigned short* Ebf  = (unsigned short*)alloc((size_t)NN * DE * 2);   // 64 KB
  unsigned short* wpT2 = (unsigned short*)alloc((size_t)JJ * DE * 2);   // 384 KB
  unsigned short* G2   = FbfT;  // FbfT dead after GEMM1; GEMM2 reads G1T/Abf/Fbf only

  prep<<<dim3(2584), 256, 0, stream>>>(feat, E, wp, bp, Fbf, FbfT, Abf, Bias, Ebf, wpT2);
  gemm_mw<1><<<dim3(1792), 256, 0, stream>>>(Abf, FbfT, G1, G1T, nullptr, Ebf, wpT2, Wg, 0);
  gemm_mw<2><<<dim3(1792), 256, 0, stream>>>(Abf, G1T, G2, nullptr, Fbf, Ebf, wpT2, Wg, 768);
  final_gemm<<<dim3(2048), 256, 0, stream>>>(Fbf, G1, G2, Wg, Bias, out);
}

// Round 8
// 215.001 us; speedup vs baseline: 2.6059x; 1.2223x over previous
//
#include <hip/hip_runtime.h>
#include <stdint.h>

// Problem constants (fixed by the reference)
#define NN 2048      // nodes
#define DE 16        // embedding dim
#define BB 64        // batch
#define CC 64        // in channels
#define OO 64        // out channels
#define BC 4096      // BB*CC
#define KR 192       // K*CC = 3*64 reduction length
#define JJ 12288     // KR*OO

using bf16x8 = __attribute__((ext_vector_type(8))) __bf16;
using f32x4  = __attribute__((ext_vector_type(4))) float;

__device__ __forceinline__ unsigned short f2bf(float f) {
  union { float f; unsigned int u; } v; v.f = f;
  unsigned int u = v.u;
  return (unsigned short)((u + 0x7FFFu + ((u >> 16) & 1u)) >> 16);  // RNE
}
__device__ __forceinline__ float bf2f(unsigned short h) {
  union { unsigned int u; float f; } v; v.u = ((unsigned int)h) << 16;
  return v.f;
}
// async global->LDS, 16B per lane. LDS dst is wave-uniform base + lane*16.
__device__ __forceinline__ void gll16(const void* g, void* l) {
  __builtin_amdgcn_global_load_lds(
      (const __attribute__((address_space(1))) unsigned int*)g,
      (__attribute__((address_space(3))) unsigned int*)l, 16, 0, 0);
}

// ---------------------------------------------------------------------------
// Kernel 1 ("prep"):
//   blocks [0,2048):    pack feat [B,N,C] fp32 -> Fbf [N][B*C] bf16 + FbfT [B*C][N]
//   blocks [2048,2560): adjacency softmax(relu(E E^T)), 4 rows per block; Bias; Ebf
//   blocks [2560,2584): permute wp fp32 -> wpT2[j][16] bf16, j = rq*512+o*8+rl
__global__ __launch_bounds__(256) void prep(const float* __restrict__ feat,
                                            const float* __restrict__ E,
                                            const float* __restrict__ wp,
                                            const float* __restrict__ bp,
                                            unsigned short* __restrict__ Fbf,
                                            unsigned short* __restrict__ FbfT,
                                            unsigned short* __restrict__ Abf,
                                            float* __restrict__ Bias,
                                            unsigned short* __restrict__ Ebf,
                                            unsigned short* __restrict__ wpT2) {
  __shared__ float smem[64 * 65];  // 16.6 KB, reused per branch
  const int id = blockIdx.x;
  const int t  = threadIdx.x;

  if (id < 2048) {
    // ---- pack_feat: b = id>>5, n-tile = (id&31)*64 ----
    float (*tile)[65] = (float (*)[65])smem;  // +1 pad: conflict-free column reads
    const int b  = id >> 5;
    const int n0 = (id & 31) * 64;
    const int tr = t >> 4, tc4 = (t & 15) * 4;
#pragma unroll
    for (int i = 0; i < 4; ++i) {
      const int r = tr + i * 16;
      const float4 v = *(const float4*)(feat + (size_t)b * (NN * CC) + (size_t)(n0 + r) * CC + tc4);
      tile[r][tc4 + 0] = v.x; tile[r][tc4 + 1] = v.y;
      tile[r][tc4 + 2] = v.z; tile[r][tc4 + 3] = v.w;
    }
    __syncthreads();
#pragma unroll
    for (int i = 0; i < 4; ++i) {
      const int r = tr + i * 16;
      const unsigned int lo = f2bf(tile[r][tc4 + 0]) | ((unsigned int)f2bf(tile[r][tc4 + 1]) << 16);
      const unsigned int hi = f2bf(tile[r][tc4 + 2]) | ((unsigned int)f2bf(tile[r][tc4 + 3]) << 16);
      *(uint2*)(Fbf + (size_t)(n0 + r) * BC + b * CC + tc4) = make_uint2(lo, hi);
    }
    // transposed store, 8B per lane (4 consecutive n)
#pragma unroll
    for (int u = 0; u < 4; ++u) {
      const int p = t + u * 256;
      const int c = p >> 4, n4 = (p & 15) * 4;
      const unsigned int lo = f2bf(tile[n4 + 0][c]) | ((unsigned int)f2bf(tile[n4 + 1][c]) << 16);
      const unsigned int hi = f2bf(tile[n4 + 2][c]) | ((unsigned int)f2bf(tile[n4 + 3][c]) << 16);
      *(uint2*)(FbfT + (size_t)(b * CC + c) * NN + n0 + n4) = make_uint2(lo, hi);
    }
  } else if (id < 2560) {
    // ---- adj_softmax, 4 rows per block (correctness verified R6/R7) ----
    const int n0base = (id - 2048) * 4;
    float* esm  = smem;        // [64]
    float* redm = smem + 64;   // [16]
    float* reds = smem + 80;   // [16]
    if (t < 64) esm[t] = E[n0base * 16 + t];
    __syncthreads();
    if (t < 64) Ebf[n0base * 16 + t] = f2bf(esm[t]);
    float er[4][16];
#pragma unroll
    for (int rr = 0; rr < 4; ++rr)
#pragma unroll
      for (int d = 0; d < 16; ++d) er[rr][d] = esm[rr * 16 + d];

    float v[8][4];
    float mx[4] = {0.f, 0.f, 0.f, 0.f};  // relu floor
#pragma unroll
    for (int i = 0; i < 8; ++i) {
      const int m = t + i * 256;
      const float4* Em = (const float4*)(E + m * 16);
      const float4 a = Em[0], b = Em[1], c = Em[2], d = Em[3];
#pragma unroll
      for (int rr = 0; rr < 4; ++rr) {
        float dot = er[rr][0] * a.x + er[rr][1] * a.y + er[rr][2] * a.z + er[rr][3] * a.w
                  + er[rr][4] * b.x + er[rr][5] * b.y + er[rr][6] * b.z + er[rr][7] * b.w
                  + er[rr][8] * c.x + er[rr][9] * c.y + er[rr][10] * c.z + er[rr][11] * c.w
                  + er[rr][12] * d.x + er[rr][13] * d.y + er[rr][14] * d.z + er[rr][15] * d.w;
        const float r = fmaxf(dot, 0.0f);
        v[i][rr] = r;
        mx[rr] = fmaxf(mx[rr], r);
      }
    }
    const int wave = t >> 6, lane = t & 63;
#pragma unroll
    for (int rr = 0; rr < 4; ++rr) {
#pragma unroll
      for (int off = 32; off > 0; off >>= 1) mx[rr] = fmaxf(mx[rr], __shfl_xor(mx[rr], off, 64));
      if (lane == 0) redm[wave * 4 + rr] = mx[rr];
    }
    __syncthreads();
#pragma unroll
    for (int rr = 0; rr < 4; ++rr)
      mx[rr] = fmaxf(fmaxf(redm[rr], redm[4 + rr]), fmaxf(redm[8 + rr], redm[12 + rr]));
    float s[4] = {0.f, 0.f, 0.f, 0.f};
#pragma unroll
    for (int i = 0; i < 8; ++i)
#pragma unroll
      for (int rr = 0; rr < 4; ++rr) { v[i][rr] = __expf(v[i][rr] - mx[rr]); s[rr] += v[i][rr]; }
#pragma unroll
    for (int rr = 0; rr < 4; ++rr) {
#pragma unroll
      for (int off = 32; off > 0; off >>= 1) s[rr] += __shfl_xor(s[rr], off, 64);
      if (lane == 0) reds[wave * 4 + rr] = s[rr];
    }
    __syncthreads();
    float inv[4];
#pragma unroll
    for (int rr = 0; rr < 4; ++rr)
      inv[rr] = 1.0f / (reds[rr] + reds[4 + rr] + reds[8 + rr] + reds[12 + rr]);
#pragma unroll
    for (int i = 0; i < 8; ++i)
#pragma unroll
      for (int rr = 0; rr < 4; ++rr)
        Abf[(size_t)(n0base + rr) * NN + t + i * 256] = f2bf(v[i][rr] * inv[rr]);
    if (t < 64) {
#pragma unroll
      for (int rr = 0; rr < 4; ++rr) {
        float bs = 0.0f;
#pragma unroll
        for (int d = 0; d < 16; ++d) bs += esm[rr * 16 + d] * bp[d * 64 + t];
        Bias[(size_t)(n0base + rr) * 64 + t] = bs;
      }
    }
  } else {
    // ---- wp permute: block rq handles j in [rq*512, rq*512+512), all 16 d ----
    const int rq = id - 2560;
    for (int p = t; p < 1024; p += 256) {
      const int e0 = p * 8;
      const int d0 = e0 & 15;        // 0 or 8
      const int rem = e0 >> 4;       // o*8 + rl
      const int rl = rem & 7, o = rem >> 3;
      const int r = rq * 8 + rl;
      unsigned int w[4];
#pragma unroll
      for (int u = 0; u < 4; ++u) {
        const float f0 = wp[(size_t)(d0 + 2 * u) * JJ + r * 64 + o];
        const float f1 = wp[(size_t)(d0 + 2 * u + 1) * JJ + r * 64 + o];
        w[u] = f2bf(f0) | ((unsigned int)f2bf(f1) << 16);
      }
      *(uint4*)(wpT2 + (size_t)rq * 8192 + e0) = make_uint4(w[0], w[1], w[2], w[3]);
    }
  }
}

// ---------------------------------------------------------------------------
// Kernel 2: 128Mx64N BK=64 bf16 MFMA GEMM — VERBATIM the measured 55-57us
// configuration (round-3 proposal): __launch_bounds__(256,4) / VGPR 48.
// (256,6) forced VGPR to 40 and caused scratch-spill WRITE inflation
// (R5/R7: +69MB write, 82-88us) — do not lower the register bound.
// XOR swizzle phys = logical ^ ((row>>1)&7): 0 LDS conflicts (measured R3).
// EPI=1 dispatch carries all 1536 make_w backfill blocks (ids >= 1024);
// EPI=2 (grid 1024): store G2 = 2*acc - F node-major.
template <int EPI, int MW>
__global__ __launch_bounds__(256, 4) void gemm_mw(const unsigned short* __restrict__ A,
                                                  const unsigned short* __restrict__ Bt,
                                                  unsigned short* __restrict__ Cnm,
                                                  unsigned short* __restrict__ Ct,
                                                  const unsigned short* __restrict__ F,
                                                  const unsigned short* __restrict__ Ebf,
                                                  const unsigned short* __restrict__ wpT2,
                                                  unsigned short* __restrict__ Wg) {
  __shared__ alignas(16) unsigned short As[128 * 64];  // 16KB
  __shared__ alignas(16) unsigned short Bs[64 * 64];   // 8KB
  const int id = blockIdx.x;
  const int t = threadIdx.x;
  const int wave = t >> 6, lane = t & 63;
  const int li = lane & 15, q = lane >> 4;

  if (MW && id >= 1024) {
    // ---- make_w: Wg[n][j] = sum_d Ebf[n][d] * wpT2[j][d], K=32 (hi 16 zero) ----
    const int wid = id - 1024;
    const int bj = (wid % 96) * 128;
    const int bm = (wid / 96) * 128;
    gll16(Ebf  + (size_t)(bm + (t >> 1)) * 16 + (t & 1) * 8, &As[t * 8]);
    gll16(wpT2 + (size_t)(bj + (t >> 1)) * 16 + (t & 1) * 8, &Bs[t * 8]);
    __syncthreads();
    const int wm = (wave >> 1) * 64, wj = (wave & 1) * 64;
    const bool hiK = (q >= 2);
    const int qq = q & 1;
    bf16x8 vz;
#pragma unroll
    for (int i = 0; i < 8; ++i) vz[i] = (__bf16)0.0f;
    bf16x8 af[4], bfr[4];
#pragma unroll
    for (int r = 0; r < 4; ++r) {
      af[r] = *(const bf16x8*)&As[(wm + r * 16 + li) * 16 + qq * 8];
      if (hiK) af[r] = vz;
    }
#pragma unroll
    for (int c = 0; c < 4; ++c) {
      bfr[c] = *(const bf16x8*)&Bs[(wj + c * 16 + li) * 16 + qq * 8];
      if (hiK) bfr[c] = vz;
    }
    const int rowL = q * 4;
#pragma unroll
    for (int r = 0; r < 4; ++r) {
#pragma unroll
      for (int c = 0; c < 4; ++c) {
        f32x4 acc = (f32x4){0.f, 0.f, 0.f, 0.f};
        acc = __builtin_amdgcn_mfma_f32_16x16x32_bf16(af[r], bfr[c], acc, 0, 0, 0);
        const int gm = bm + wm + r * 16 + rowL;
        const int gj = bj + wj + c * 16 + li;
#pragma unroll
        for (int i = 0; i < 4; ++i)
          Wg[(size_t)(gm + i) * JJ + gj] = f2bf(acc[i]);
      }
    }
    return;
  }

  // ---- GEMM: bm=(id>>6)*128, bn=(id&63)*64 (locality-agnostic mapping) ----
  const int bm = (id >> 6) * 128, bn = (id & 63) * 64;
  const int wm = wave * 32;  // wave covers 32 M-rows x 64 N-cols

  f32x4 acc[2][4];
#pragma unroll
  for (int r = 0; r < 2; ++r)
#pragma unroll
    for (int c = 0; c < 4; ++c) acc[r][c] = (f32x4){0.f, 0.f, 0.f, 0.f};

  // staging: A 1024 chunks (4/thread), B 512 chunks (2/thread), 16B each.
  // chunk c: row = c>>3, pos = c&7; phys pos holds logical pos ^ ((row>>1)&7).
  const int srow = t >> 3;
  const int csw = (((t & 7) ^ ((t >> 4) & 7)) * 8);        // swizzled col (elems)
  const unsigned short* Ap[4];
  const unsigned short* Bp[2];
#pragma unroll
  for (int i = 0; i < 4; ++i) Ap[i] = A + (size_t)(bm + srow + i * 32) * NN + csw;
#pragma unroll
  for (int i = 0; i < 2; ++i) Bp[i] = Bt + (size_t)(bn + srow + i * 32) * NN + csw;
  const int sw = (li >> 1) & 7;

  for (int k0 = 0; k0 < NN; k0 += 64) {
    __syncthreads();  // prior-iter LDS reads done before overwrite
#pragma unroll
    for (int i = 0; i < 4; ++i) gll16(Ap[i] + k0, &As[(t + i * 256) * 8]);
#pragma unroll
    for (int i = 0; i < 2; ++i) gll16(Bp[i] + k0, &Bs[(t + i * 256) * 8]);
    __syncthreads();  // compiler drains vmcnt before s_barrier
#pragma unroll
    for (int kk = 0; kk < 2; ++kk) {
      const int kc = ((kk * 4 + q) ^ sw) * 8;
      bf16x8 af[2], bfr[4];
#pragma unroll
      for (int r = 0; r < 2; ++r)
        af[r] = *(const bf16x8*)&As[(wm + r * 16 + li) * 64 + kc];
#pragma unroll
      for (int c = 0; c < 4; ++c)
        bfr[c] = *(const bf16x8*)&Bs[(c * 16 + li) * 64 + kc];
#pragma unroll
      for (int r = 0; r < 2; ++r)
#pragma unroll
        for (int c = 0; c < 4; ++c)
          acc[r][c] = __builtin_amdgcn_mfma_f32_16x16x32_bf16(af[r], bfr[c], acc[r][c], 0, 0, 0);
    }
  }

  const int rowL = q * 4;  // C/D: col=lane&15, row=quad*4+i
#pragma unroll
  for (int r = 0; r < 2; ++r) {
#pragma unroll
    for (int c = 0; c < 4; ++c) {
      const int gm = bm + wm + r * 16 + rowL;
      const int gn = bn + c * 16 + li;
      const f32x4 a = acc[r][c];
      if (EPI == 1) {
#pragma unroll
        for (int i = 0; i < 4; ++i)
          Cnm[(size_t)(gm + i) * BC + gn] = f2bf(a[i]);
        const unsigned int lo = f2bf(a[0]) | ((unsigned int)f2bf(a[1]) << 16);
        const unsigned int hi = f2bf(a[2]) | ((unsigned int)f2bf(a[3]) << 16);
        *(uint2*)(Ct + (size_t)gn * NN + gm) = make_uint2(lo, hi);  // gm%4==0 -> 8B aligned
      } else {
#pragma unroll
        for (int i = 0; i < 4; ++i) {
          const float g = 2.0f * a[i] - bf2f(F[(size_t)(gm + i) * BC + gn]);
          Cnm[(size_t)(gm + i) * BC + gn] = f2bf(g);
        }
      }
    }
  }
}

// ---------------------------------------------------------------------------
// Kernel 3: per-node GEMM out[b,n,o] = X_n[64,192] @ W_n[192,64] + bias[n,o].
// LDS-free, barrier-free (correct in R5-R7): K8-blocked Wg + node-major X
// make every MFMA fragment a coalesced 16B global load (direct global->VGPR).
__global__ __launch_bounds__(256, 6) void final_gemm(const unsigned short* __restrict__ Fbf,
                                                     const unsigned short* __restrict__ G1,
                                                     const unsigned short* __restrict__ G2,
                                                     const unsigned short* __restrict__ Wg,
                                                     const float* __restrict__ Bias,
                                                     float* __restrict__ out) {
  const int n = blockIdx.x, t = threadIdx.x;
  const int wave = t >> 6, lane = t & 63;
  const int li = lane & 15, q = lane >> 4;
  const unsigned short* xb[3] = {Fbf + (size_t)n * BC + (size_t)(wave * 16 + li) * 64,
                                 G1  + (size_t)n * BC + (size_t)(wave * 16 + li) * 64,
                                 G2  + (size_t)n * BC + (size_t)(wave * 16 + li) * 64};
  const unsigned short* wb = Wg + (size_t)n * JJ + (size_t)q * 512 + li * 8;

  f32x4 acc[4];
#pragma unroll
  for (int c = 0; c < 4; ++c) acc[c] = (f32x4){0.f, 0.f, 0.f, 0.f};
#pragma unroll
  for (int kq = 0; kq < 6; ++kq) {
    const bf16x8 a = *(const bf16x8*)(xb[kq >> 1] + (kq & 1) * 32 + q * 8);
#pragma unroll
    for (int c = 0; c < 4; ++c) {
      const bf16x8 b = *(const bf16x8*)(wb + (size_t)kq * 2048 + c * 128);
      acc[c] = __builtin_amdgcn_mfma_f32_16x16x32_bf16(a, b, acc[c], 0, 0, 0);
    }
  }
  const int rbase = wave * 16 + q * 4;
#pragma unroll
  for (int c = 0; c < 4; ++c) {
    const int o = c * 16 + li;
    const float bs = Bias[n * 64 + o];
#pragma unroll
    for (int i = 0; i < 4; ++i)
      out[(size_t)(rbase + i) * (NN * OO) + (size_t)n * OO + o] = acc[c][i] + bs;
  }
}

// ---------------------------------------------------------------------------
extern "C" void kernel_launch(void* const* d_in, const int* in_sizes, int n_in,
                              void* d_out, int out_size, void* d_ws, size_t ws_size,
                              hipStream_t stream) {
  const float* E    = (const float*)d_in[0];  // [2048,16]
  const float* feat = (const float*)d_in[1];  // [64,2048,64]
  const float* wp   = (const float*)d_in[2];  // [16,3,64,64]
  const float* bp   = (const float*)d_in[3];  // [16,64]
  float* out = (float*)d_out;

  char* ws = (char*)d_ws;
  size_t off = 0;
  auto alloc = [&](size_t bytes) -> void* {
    void* p = ws + off;
    off += (bytes + 255) & ~(size_t)255;
    return p;
  };
  unsigned short* Abf  = (unsigned short*)alloc((size_t)NN * NN * 2);   //  8 MB
  unsigned short* FbfT = (unsigned short*)alloc((size_t)BC * NN * 2);   // 16 MB (reused as G2)
  unsigned short* Fbf  = (unsigned short*)alloc((size_t)NN * BC * 2);   // 16 MB
  unsigned short* G1   = (unsigned short*)alloc((size_t)NN * BC * 2);   // 16 MB
  unsigned short* G1T  = (unsigned short*)alloc((size_t)BC * NN * 2);   // 16 MB
  unsigned short* Wg   = (unsigned short*)alloc((size_t)NN * JJ * 2);   // 48 MB
  float* Bias          = (float*)alloc((size_t)NN * OO * 4);            // 0.5 MB
  unsigned short* Ebf  = (unsigned short*)alloc((size_t)NN * DE * 2);   // 64 KB
  unsigned short* wpT2 = (unsigned short*)alloc((size_t)JJ * DE * 2);   // 384 KB
  unsigned short* G2   = FbfT;  // FbfT dead after GEMM1; GEMM2 reads G1T/Abf/Fbf only

  prep<<<dim3(2584), 256, 0, stream>>>(feat, E, wp, bp, Fbf, FbfT, Abf, Bias, Ebf, wpT2);
  gemm_mw<1, 1><<<dim3(2560), 256, 0, stream>>>(Abf, FbfT, G1, G1T, nullptr, Ebf, wpT2, Wg);
  gemm_mw<2, 0><<<dim3(1024), 256, 0, stream>>>(Abf, G1T, G2, nullptr, Fbf, Ebf, wpT2, Wg);
  final_gemm<<<dim3(2048), 256, 0, stream>>>(Fbf, G1, G2, Wg, Bias, out);
}